// Round 17
// baseline (238.508 us; speedup 1.0000x reference)
//
#include <hip/hip_runtime.h>
#include <math.h>

typedef __attribute__((ext_vector_type(8))) short bf8;
typedef __attribute__((ext_vector_type(4))) float f32x4;

#define BSHIFT 8   // 256 nodes per bucket

__device__ __forceinline__ float lrelu(float v){ return fmaxf(v, 0.01f * v); }

__device__ __forceinline__ float wave_sum(float v){
#pragma unroll
  for (int s = 32; s > 0; s >>= 1) v += __shfl_xor(v, s);
  return v;
}
__device__ __forceinline__ float wave_max(float v){
#pragma unroll
  for (int s = 32; s > 0; s >>= 1) v = fmaxf(v, __shfl_xor(v, s));
  return v;
}

__device__ __forceinline__ float bcast(float v, int k){
  return __uint_as_float((unsigned)__builtin_amdgcn_readlane(__float_as_uint(v), k));
}

// float -> orderable unsigned key (monotone)
__device__ __forceinline__ unsigned fkey(float x){
  unsigned u = __float_as_uint(x);
  return (u & 0x80000000u) ? ~u : (u | 0x80000000u);
}
__device__ __forceinline__ float funkey(unsigned k){
  unsigned u = (k & 0x80000000u) ? (k & 0x7fffffffu) : ~k;
  return __uint_as_float(u);
}

// float -> bf16 (RNE)
__device__ __forceinline__ short f2bfs(float x){
  unsigned u = __float_as_uint(x);
  return (short)((u + 0x7fffu + ((u >> 16) & 1u)) >> 16);
}
__device__ __forceinline__ float bf2f(ushort v){
  return __uint_as_float((unsigned)v << 16);
}
__device__ __forceinline__ bf8 pack8(float4 a, float4 b){
  bf8 v;
  v[0]=f2bfs(a.x); v[1]=f2bfs(a.y); v[2]=f2bfs(a.z); v[3]=f2bfs(a.w);
  v[4]=f2bfs(b.x); v[5]=f2bfs(b.y); v[6]=f2bfs(b.z); v[7]=f2bfs(b.w);
  return v;
}
__device__ __forceinline__ float4 xo4(float nav, float4 w, float4 b){
  float4 r;
  r.x = lrelu(nav*w.x + b.x); r.y = lrelu(nav*w.y + b.y);
  r.z = lrelu(nav*w.z + b.z); r.w = lrelu(nav*w.w + b.w);
  return r;
}
__device__ __forceinline__ float dot4(float4 a, float4 b){
  return a.x*b.x + a.y*b.y + a.z*b.z + a.w*b.w;
}

// ---------------- weight transpose to k-major (small weights for 1-wave kernels) ----------------
__global__ void k_wprep(const float* __restrict__ wg1, const float* __restrict__ wm,
                        const float* __restrict__ w2,
                        const float* __restrict__ g2wih, const float* __restrict__ g2whh,
                        float* __restrict__ wm_t, float* __restrict__ w2_t,
                        float* __restrict__ g2ih_t, float* __restrict__ g2hh_t,
                        float* __restrict__ wgc){
  int k = blockIdx.x;      // 0..63
  int r = threadIdx.x;     // 0..191
  if (r < 64){
    wm_t [k * 64 + r] = wm [r * 64 + k];
    w2_t [k * 64 + r] = w2 [r * 64 + k];
    if (k == 0) wgc[r] = wg1[r * 65 + 64];
  }
  g2ih_t[k * 192 + r] = g2wih[r * 64 + k];
  g2hh_t[k * 192 + r] = g2whh[r * 64 + k];
}

// ---------------- pack weights into bf16 MFMA B-fragments ----------------
__global__ void k_wfrag(const float* __restrict__ wg2, const float* __restrict__ wm,
                        const float* __restrict__ wg1,
                        const float* __restrict__ wih, const float* __restrict__ whh,
                        ushort* __restrict__ wg2f, ushort* __restrict__ wmf,
                        ushort* __restrict__ wg1f,
                        ushort* __restrict__ wihf, ushort* __restrict__ whhf){
  int tid = blockIdx.x * 256 + threadIdx.x;  // 0..4607
  if (tid >= 4608) return;
  const float* W; ushort* F; int T, S, base;
  if (tid < 512)      { W = wg2; F = wg2f; T = 4;  S = 64; base = tid; }
  else if (tid < 1024){ W = wm;  F = wmf;  T = 4;  S = 64; base = tid - 1024 + 512; }
  else if (tid < 1536){ W = wg1; F = wg1f; T = 4;  S = 65; base = tid - 1024; }
  else if (tid < 3072){ W = wih; F = wihf; T = 12; S = 64; base = tid - 1536; }
  else                { W = whh; F = whhf; T = 12; S = 64; base = tid - 3072; }
  int l  = base & 63;
  int ct = base >> 6;
  int c  = ct / T, t = ct - c * T;
  int row = 16 * t + (l & 15);
  int k0  = 32 * c + (l >> 4) * 8;
  const float* src = W + row * S + k0;
  unsigned o0 = (unsigned)(ushort)f2bfs(src[0]) | ((unsigned)(ushort)f2bfs(src[1]) << 16);
  unsigned o1 = (unsigned)(ushort)f2bfs(src[2]) | ((unsigned)(ushort)f2bfs(src[3]) << 16);
  unsigned o2 = (unsigned)(ushort)f2bfs(src[4]) | ((unsigned)(ushort)f2bfs(src[5]) << 16);
  unsigned o3 = (unsigned)(ushort)f2bfs(src[6]) | ((unsigned)(ushort)f2bfs(src[7]) << 16);
  ((uint4*)F)[base] = make_uint4(o0, o1, o2, o3);
}

// ---------------- FUSED node prep (blocks 0..511) + bucket histogram (blocks 512..) ----------------
__global__ __launch_bounds__(256) void k_node_bh(
    const float* __restrict__ na, const float* __restrict__ w1,
    const float* __restrict__ b1, const ushort* __restrict__ wg1f,
    const float* __restrict__ att_r,
    ushort* __restrict__ yb, float* __restrict__ xr, int N,
    const int* __restrict__ dst, int* __restrict__ bcnt, int E, int nbuck){
  if (blockIdx.x >= 512){
    __shared__ int hist[512];
    hist[threadIdx.x] = 0; hist[256 + threadIdx.x] = 0;
    __syncthreads();
    int bid = blockIdx.x - 512;
    int e0 = bid * 4096;
    int e1 = min(e0 + 4096, E);
    for (int i = e0 + threadIdx.x; i < e1; i += 256)
      atomicAdd(&hist[dst[i] >> BSHIFT], 1);
    __syncthreads();
#pragma unroll
    for (int q = 0; q < 2; q++){
      int j = threadIdx.x + q * 256;
      if (j < nbuck && hist[j] > 0) atomicAdd(&bcnt[j], hist[j]);
    }
    return;
  }
  int lane = threadIdx.x & 63;
  int wid  = threadIdx.x >> 6;
  int m = lane & 15, g = lane >> 4;
  const bf8* WG = (const bf8*)wg1f;
  float4 w1a = *(const float4*)(w1 + g*8),      w1b = *(const float4*)(w1 + g*8 + 4);
  float4 w1c = *(const float4*)(w1 + 32 + g*8), w1d = *(const float4*)(w1 + 32 + g*8 + 4);
  float4 b1a = *(const float4*)(b1 + g*8),      b1b = *(const float4*)(b1 + g*8 + 4);
  float4 b1c = *(const float4*)(b1 + 32 + g*8), b1d = *(const float4*)(b1 + 32 + g*8 + 4);
  float4 ara = *(const float4*)(att_r + g*8),      arb = *(const float4*)(att_r + g*8 + 4);
  float4 arc = *(const float4*)(att_r + 32 + g*8), ard = *(const float4*)(att_r + 32 + g*8 + 4);
  int ntiles = (N + 15) >> 4;
  for (int tile = blockIdx.x * 4 + wid; tile < ntiles; tile += 512 * 4){
    int n0 = tile * 16;
    int row = n0 + m;
    bool valid = row < N;
    float nav = valid ? na[row] : 0.f;
    float4 x0 = xo4(nav, w1a, b1a), x1 = xo4(nav, w1b, b1b);
    float4 x2 = xo4(nav, w1c, b1c), x3 = xo4(nav, w1d, b1d);
    float xa = dot4(x0, ara) + dot4(x1, arb) + dot4(x2, arc) + dot4(x3, ard);
    xa += __shfl_xor(xa, 16); xa += __shfl_xor(xa, 32);
    if (g == 0 && valid) xr[row] = xa;
    bf8 fa0 = pack8(x0, x1), fa1 = pack8(x2, x3);
    f32x4 yt[4];
#pragma unroll
    for (int t = 0; t < 4; t++){
      f32x4 acc = {0.f, 0.f, 0.f, 0.f};
      acc = __builtin_amdgcn_mfma_f32_16x16x32_bf16(fa0, WG[t * 64 + lane], acc, 0, 0, 0);
      acc = __builtin_amdgcn_mfma_f32_16x16x32_bf16(fa1, WG[(4 + t) * 64 + lane], acc, 0, 0, 0);
      yt[t] = acc;
    }
#pragma unroll
    for (int t = 0; t < 4; t++){
#pragma unroll
      for (int r = 0; r < 4; r++){
        int rw = n0 + g * 4 + r;
        if (rw < N) yb[(size_t)rw * 64 + m + 16 * t] = (ushort)f2bfs(yt[t][r]);
      }
    }
  }
}

// ---------------- bucket prefix scan (1 block, 512 threads) ----------------
__global__ void k_bscan(const int* __restrict__ bcnt, int* __restrict__ bbase,
                        int* __restrict__ gtail, int nbuck){
  __shared__ int lds[512];
  int t = threadIdx.x;
  int v = (t < nbuck) ? bcnt[t] : 0;
  lds[t] = v;
  __syncthreads();
  for (int s = 1; s < 512; s <<= 1){
    int tv = (t >= s) ? lds[t - s] : 0;
    __syncthreads();
    lds[t] += tv;
    __syncthreads();
  }
  if (t <= nbuck){
    int excl = (t == 0) ? 0 : lds[t - 1];
    bbase[t] = excl;
    if (t < nbuck) gtail[t] = excl;
  }
}

// ---------------- binned scatter phase A ----------------
__global__ __launch_bounds__(256) void k_binA(
    const int* __restrict__ dst, const int* __restrict__ src,
    const float* __restrict__ ea, int* __restrict__ gtail,
    int2* __restrict__ tse, int E){
  __shared__ int hist[512], base[512], run[512];
  int e0 = blockIdx.x * 4096;
  int e1 = min(e0 + 4096, E);
  hist[threadIdx.x] = 0; hist[256 + threadIdx.x] = 0;
  run[threadIdx.x] = 0;  run[256 + threadIdx.x] = 0;
  __syncthreads();
  for (int i = e0 + threadIdx.x; i < e1; i += 256)
    atomicAdd(&hist[dst[i] >> BSHIFT], 1);
  __syncthreads();
#pragma unroll
  for (int q = 0; q < 2; q++){
    int j = threadIdx.x + q * 256;
    if (hist[j] > 0) base[j] = atomicAdd(&gtail[j], hist[j]);
  }
  __syncthreads();
  for (int i = e0 + threadIdx.x; i < e1; i += 256){
    int d = dst[i];
    int b = d >> BSHIFT;
    int pos = base[b] + atomicAdd(&run[b], 1);
    tse[pos] = make_int2(src[i] | ((d & 255) << 17), __float_as_int(ea[i]));
  }
}

// ---------------- binned scatter phase B: per-node offsets + place + degree-class hist ----------------
__global__ __launch_bounds__(256) void k_binB(
    const int* __restrict__ bbase, const int2* __restrict__ tse,
    int2* __restrict__ csr, int* __restrict__ off, int* __restrict__ dcnt, int N){
  __shared__ int degL[256];
  __shared__ int fillL[256];
  __shared__ int dh[64];
  int node0 = blockIdx.x << BSHIFT;
  int node1 = min(node0 + 256, N);
  int nn = node1 - node0;
  int i0 = bbase[blockIdx.x], i1 = bbase[blockIdx.x + 1];
  int t = threadIdx.x;
  degL[t] = 0;
  if (t < 64) dh[t] = 0;
  __syncthreads();
  for (int i = i0 + t; i < i1; i += 256)
    atomicAdd(&degL[(tse[i].x >> 17) & 255], 1);
  __syncthreads();
  int rawdeg = degL[t];
  if (t < nn) atomicAdd(&dh[min(rawdeg, 63)], 1);
  for (int s = 1; s < 256; s <<= 1){
    int v = (t >= s) ? degL[t - s] : 0;
    __syncthreads();
    degL[t] += v;
    __syncthreads();
  }
  int prev = (t == 0) ? 0 : degL[t - 1];
  fillL[t] = i0 + prev;
  if (t < nn) off[node0 + t] = i0 + prev;
  if (t == 0 && node1 == N) off[N] = i1;
  __syncthreads();
  if (t < 64 && dh[t] > 0) atomicAdd(&dcnt[t], dh[t]);
  for (int i = i0 + t; i < i1; i += 256){
    int2 rec = tse[i];
    int drel = (rec.x >> 17) & 255;
    int pos = atomicAdd(&fillL[drel], 1);
    csr[pos] = make_int2(rec.x & 0x1FFFF, rec.y);
  }
}

// ---------------- degree-class scan (1 block, 64 threads) ----------------
__global__ void k_dscan(const int* __restrict__ dcnt, int* __restrict__ dtail){
  __shared__ int lds[64];
  int t = threadIdx.x;
  lds[t] = dcnt[t];
  __syncthreads();
  for (int s = 1; s < 64; s <<= 1){
    int v = (t >= s) ? lds[t - s] : 0;
    __syncthreads();
    lds[t] += v;
    __syncthreads();
  }
  dtail[t] = (t == 0) ? 0 : lds[t - 1];
}

// ---------------- build degree-sorted node permutation (LDS-aggregated) ----------------
__global__ __launch_bounds__(256) void k_dfill(const int* __restrict__ off,
                                               int* __restrict__ dtail,
                                               int* __restrict__ perm, int N){
  __shared__ int hist[64], base[64], run[64];
  int n0 = blockIdx.x * 4096;
  int n1 = min(n0 + 4096, N);
  if (threadIdx.x < 64){ hist[threadIdx.x] = 0; run[threadIdx.x] = 0; }
  __syncthreads();
  for (int n = n0 + threadIdx.x; n < n1; n += 256)
    atomicAdd(&hist[min(off[n + 1] - off[n], 63)], 1);
  __syncthreads();
  if (threadIdx.x < 64 && hist[threadIdx.x] > 0)
    base[threadIdx.x] = atomicAdd(&dtail[threadIdx.x], hist[threadIdx.x]);
  __syncthreads();
  for (int n = n0 + threadIdx.x; n < n1; n += 256){
    int c = min(off[n + 1] - off[n], 63);
    int pos = base[c] + atomicAdd(&run[c], 1);
    perm[pos] = n;
  }
}

// ---------------- fused edge kernel: 4 nodes/wave (degree-batched via perm) ----------------
__global__ void k_edge_f(const int* __restrict__ off, const int2* __restrict__ csr,
                         const ushort* __restrict__ yb, const float* __restrict__ xr,
                         const float* __restrict__ wgc, const float* __restrict__ att_l,
                         const int* __restrict__ perm,
                         float* __restrict__ sout, int N){
  int lane = threadIdx.x & 63;
  int wwid = (blockIdx.x * blockDim.x + threadIdx.x) >> 6;
  int g = lane >> 4, sl = lane & 15;
  int idx = wwid * 4 + g;
  if (idx >= N) return;
  int node = perm[idx];
  int i0 = off[node], i1 = off[node + 1];
  float4 wc4 = ((const float4*)wgc)[sl];
  float4 al4 = ((const float4*)att_l)[sl];
  float xrn = xr[node];
  float sg = 0.f;
  float4 acc = make_float4(0.f, 0.f, 0.f, 0.f);
  int cnt = i1 - i0;
  int2 rA = make_int2(0,0), rB = rA, rC = rA, rD = rA;
  ushort4 yA = make_ushort4(0,0,0,0), yB = yA, yC = yA, yD = yA;
  if (cnt > 0){ rA = csr[i0];     yA = ((const ushort4*)(yb + (size_t)rA.x * 64))[sl]; }
  if (cnt > 1){ rB = csr[i0 + 1]; yB = ((const ushort4*)(yb + (size_t)rB.x * 64))[sl]; }
  if (cnt > 2){ rC = csr[i0 + 2]; yC = ((const ushort4*)(yb + (size_t)rC.x * 64))[sl]; }
  if (cnt > 3){ rD = csr[i0 + 3]; yD = ((const ushort4*)(yb + (size_t)rD.x * 64))[sl]; }
  int i = i0;
  for (; i + 1 < i1; i += 2){
    float eaA = __int_as_float(rA.y);
    float eaB = __int_as_float(rB.y);
    float4 heA, heB;
    heA.x = lrelu(bf2f(yA.x) + eaA * wc4.x); heB.x = lrelu(bf2f(yB.x) + eaB * wc4.x);
    heA.y = lrelu(bf2f(yA.y) + eaA * wc4.y); heB.y = lrelu(bf2f(yB.y) + eaB * wc4.y);
    heA.z = lrelu(bf2f(yA.z) + eaA * wc4.z); heB.z = lrelu(bf2f(yB.z) + eaB * wc4.z);
    heA.w = lrelu(bf2f(yA.w) + eaA * wc4.w); heB.w = lrelu(bf2f(yB.w) + eaB * wc4.w);
    rA = rC; yA = yC; rB = rD; yB = yD;
    if (i + 4 < i1){ rC = csr[i + 4]; yC = ((const ushort4*)(yb + (size_t)rC.x * 64))[sl]; }
    if (i + 5 < i1){ rD = csr[i + 5]; yD = ((const ushort4*)(yb + (size_t)rD.x * 64))[sl]; }
    float pA = dot4(heA, al4), pB = dot4(heB, al4);
    pA += __shfl_xor(pA, 1); pB += __shfl_xor(pB, 1);
    pA += __shfl_xor(pA, 2); pB += __shfl_xor(pB, 2);
    pA += __shfl_xor(pA, 4); pB += __shfl_xor(pB, 4);
    pA += __shfl_xor(pA, 8); pB += __shfl_xor(pB, 8);
    float wa = __expf(lrelu(pA + xrn));
    float wb = __expf(lrelu(pB + xrn));
    sg += wa + wb;
    acc.x += wa * heA.x + wb * heB.x;
    acc.y += wa * heA.y + wb * heB.y;
    acc.z += wa * heA.z + wb * heB.z;
    acc.w += wa * heA.w + wb * heB.w;
  }
  if (i < i1){
    float ea = __int_as_float(rA.y);
    float4 he;
    he.x = lrelu(bf2f(yA.x) + ea * wc4.x);
    he.y = lrelu(bf2f(yA.y) + ea * wc4.y);
    he.z = lrelu(bf2f(yA.z) + ea * wc4.z);
    he.w = lrelu(bf2f(yA.w) + ea * wc4.w);
    float p = dot4(he, al4);
    p += __shfl_xor(p, 1); p += __shfl_xor(p, 2);
    p += __shfl_xor(p, 4); p += __shfl_xor(p, 8);
    float w = __expf(lrelu(p + xrn));
    sg += w;
    acc.x += w * he.x; acc.y += w * he.y;
    acc.z += w * he.z; acc.w += w * he.w;
  }
  float inv = (i1 > i0 && sg > 0.f) ? 1.f / sg : 0.f;
  float4 o = make_float4(acc.x * inv, acc.y * inv, acc.z * inv, acc.w * inv);
  ((float4*)(sout + (size_t)node * 64))[sl] = o;
}

// ---------------- GRU1 via MFMA: writes x2 as bf16 ----------------
__global__ __launch_bounds__(256) void k_gru1m(
    const float* __restrict__ sout, const float* __restrict__ na,
    const float* __restrict__ w1, const float* __restrict__ b1,
    const ushort* __restrict__ wg2f, const float* __restrict__ bg,
    const ushort* __restrict__ wihf, const ushort* __restrict__ whhf,
    const float* __restrict__ bih, const float* __restrict__ bhh,
    ushort* __restrict__ x2b, int N){
  __shared__ ushort xgl[4][16][72];   // per-wave elu(h) tile, bf16, padded rows
  int lane = threadIdx.x & 63;
  int wid  = threadIdx.x >> 6;
  int m = lane & 15, g = lane >> 4;
  int n0 = blockIdx.x * 64 + wid * 16;
  if (n0 >= N) return;                 // no barriers used -> safe early exit
  int rowc = min(n0 + m, N - 1);
  const float* srow = sout + (size_t)rowc * 64;
  bf8 sa0 = pack8(*(const float4*)(srow + g * 8),      *(const float4*)(srow + g * 8 + 4));
  bf8 sa1 = pack8(*(const float4*)(srow + 32 + g * 8), *(const float4*)(srow + 32 + g * 8 + 4));
  const bf8* WG = (const bf8*)wg2f;
  f32x4 h[4];
#pragma unroll
  for (int t = 0; t < 4; t++){
    f32x4 acc = {0.f, 0.f, 0.f, 0.f};
    acc = __builtin_amdgcn_mfma_f32_16x16x32_bf16(sa0, WG[t * 64 + lane], acc, 0, 0, 0);
    acc = __builtin_amdgcn_mfma_f32_16x16x32_bf16(sa1, WG[(4 + t) * 64 + lane], acc, 0, 0, 0);
    h[t] = acc;
  }
#pragma unroll
  for (int t = 0; t < 4; t++){
    float bgc = bg[m + 16 * t];
#pragma unroll
    for (int r = 0; r < 4; r++){
      float hv = h[t][r] + bgc;
      float xg = hv > 0.f ? hv : __expf(hv) - 1.f;
      xgl[wid][g * 4 + r][m + 16 * t] = (ushort)f2bfs(xg);
    }
  }
  float nav = na[rowc];
  bf8 xoa0 = pack8(xo4(nav, *(const float4*)(w1 + g * 8),      *(const float4*)(b1 + g * 8)),
                   xo4(nav, *(const float4*)(w1 + g * 8 + 4),  *(const float4*)(b1 + g * 8 + 4)));
  bf8 xoa1 = pack8(xo4(nav, *(const float4*)(w1 + 32 + g * 8),     *(const float4*)(b1 + 32 + g * 8)),
                   xo4(nav, *(const float4*)(w1 + 32 + g * 8 + 4), *(const float4*)(b1 + 32 + g * 8 + 4)));
  bf8 xga0 = *(const bf8*)&xgl[wid][m][g * 8];
  bf8 xga1 = *(const bf8*)&xgl[wid][m][32 + g * 8];
  const bf8* WI = (const bf8*)wihf;
  const bf8* WH = (const bf8*)whhf;
#pragma unroll
  for (int t = 0; t < 4; t++){
    f32x4 iR = {0.f,0.f,0.f,0.f}, iZ = iR, iN = iR, hR = iR, hZ = iR, hN = iR;
    iR = __builtin_amdgcn_mfma_f32_16x16x32_bf16(xga0, WI[(t     ) * 64 + lane], iR, 0,0,0);
    iR = __builtin_amdgcn_mfma_f32_16x16x32_bf16(xga1, WI[(12 + t) * 64 + lane], iR, 0,0,0);
    iZ = __builtin_amdgcn_mfma_f32_16x16x32_bf16(xga0, WI[(t +  4) * 64 + lane], iZ, 0,0,0);
    iZ = __builtin_amdgcn_mfma_f32_16x16x32_bf16(xga1, WI[(16 + t) * 64 + lane], iZ, 0,0,0);
    iN = __builtin_amdgcn_mfma_f32_16x16x32_bf16(xga0, WI[(t +  8) * 64 + lane], iN, 0,0,0);
    iN = __builtin_amdgcn_mfma_f32_16x16x32_bf16(xga1, WI[(20 + t) * 64 + lane], iN, 0,0,0);
    hR = __builtin_amdgcn_mfma_f32_16x16x32_bf16(xoa0, WH[(t     ) * 64 + lane], hR, 0,0,0);
    hR = __builtin_amdgcn_mfma_f32_16x16x32_bf16(xoa1, WH[(12 + t) * 64 + lane], hR, 0,0,0);
    hZ = __builtin_amdgcn_mfma_f32_16x16x32_bf16(xoa0, WH[(t +  4) * 64 + lane], hZ, 0,0,0);
    hZ = __builtin_amdgcn_mfma_f32_16x16x32_bf16(xoa1, WH[(16 + t) * 64 + lane], hZ, 0,0,0);
    hN = __builtin_amdgcn_mfma_f32_16x16x32_bf16(xoa0, WH[(t +  8) * 64 + lane], hN, 0,0,0);
    hN = __builtin_amdgcn_mfma_f32_16x16x32_bf16(xoa1, WH[(20 + t) * 64 + lane], hN, 0,0,0);
    int col = m + 16 * t;
    float biR = bih[col], biZ = bih[64 + col], biN = bih[128 + col];
    float bhR = bhh[col], bhZ = bhh[64 + col], bhN = bhh[128 + col];
    float w1c = w1[col], b1c = b1[col];
#pragma unroll
    for (int r = 0; r < 4; r++){
      int node = n0 + g * 4 + r;
      if (node < N){
        float xon = lrelu(na[node] * w1c + b1c);
        float rg = 1.f / (1.f + __expf(-(iR[r] + biR + hR[r] + bhR)));
        float zg = 1.f / (1.f + __expf(-(iZ[r] + biZ + hZ[r] + bhZ)));
        float nn = tanhf(iN[r] + biN + rg * (hN[r] + bhN));
        float xn = (1.f - zg) * nn + zg * xon;
        x2b[(size_t)node * 64 + col] = (ushort)f2bfs(fmaxf(xn, 0.f));
      }
    }
  }
}

// ---------------- part2 via MFMA: reads x2 bf16 (A-frags direct), writes xs bf16 ----------------
__global__ __launch_bounds__(256) void k_part2m(
    const ushort* __restrict__ x2b, ushort* __restrict__ xsb,
    const ushort* __restrict__ wmf, const float* __restrict__ att_src,
    float* __restrict__ tb, float* __restrict__ scal, int N){
  int lane = threadIdx.x & 63;
  int wid  = threadIdx.x >> 6;
  int m = lane & 15, g = lane >> 4;
  const bf8* WM = (const bf8*)wmf;
  float as_t[4];
#pragma unroll
  for (int t = 0; t < 4; t++) as_t[t] = att_src[m + 16 * t];
  float os[16];
#pragma unroll
  for (int j = 0; j < 16; j++) os[j] = 0.f;
  float tmax = -1e30f;
  int ntiles = (N + 15) >> 4;
  for (int tile = blockIdx.x * 4 + wid; tile < ntiles; tile += gridDim.x * 4){
    int n0 = tile * 16;
    int row = n0 + m;
    bool valid = row < N;
    int rowc = valid ? row : (N - 1);
    const ushort* xrow = x2b + (size_t)rowc * 64;
    bf8 fa0 = *(const bf8*)(xrow + g * 8);
    bf8 fa1 = *(const bf8*)(xrow + 32 + g * 8);
    if (!valid){
#pragma unroll
      for (int j = 0; j < 8; j++){ fa0[j] = 0; fa1[j] = 0; }
    }
#pragma unroll
    for (int j = 0; j < 8; j++){
      os[j]     += bf2f((ushort)fa0[j]);
      os[8 + j] += bf2f((ushort)fa1[j]);
    }
    f32x4 xs_t[4];
#pragma unroll
    for (int t = 0; t < 4; t++){
      f32x4 acc = {0.f, 0.f, 0.f, 0.f};
      acc = __builtin_amdgcn_mfma_f32_16x16x32_bf16(fa0, WM[t * 64 + lane], acc, 0, 0, 0);
      acc = __builtin_amdgcn_mfma_f32_16x16x32_bf16(fa1, WM[(4 + t) * 64 + lane], acc, 0, 0, 0);
      xs_t[t] = acc;
    }
    float tpart[4] = {0.f, 0.f, 0.f, 0.f};
#pragma unroll
    for (int t = 0; t < 4; t++){
#pragma unroll
      for (int r = 0; r < 4; r++){
        int rw = n0 + g * 4 + r;
        if (rw < N) xsb[(size_t)rw * 64 + m + 16 * t] = (ushort)f2bfs(xs_t[t][r]);
        tpart[r] += xs_t[t][r] * as_t[t];
      }
    }
#pragma unroll
    for (int r = 0; r < 4; r++){
      float v = tpart[r];
      v += __shfl_xor(v, 1); v += __shfl_xor(v, 2);
      v += __shfl_xor(v, 4); v += __shfl_xor(v, 8);
      if (m == 0){
        int rw = n0 + g * 4 + r;
        if (rw < N){ tb[rw] = v; tmax = fmaxf(tmax, v); }
      }
    }
  }
  tmax = wave_max(tmax);
  if (lane == 0) atomicMax((unsigned*)(scal + 131), fkey(tmax));
#pragma unroll
  for (int j = 0; j < 16; j++){
    float v = os[j];
    v += __shfl_xor(v, 1); v += __shfl_xor(v, 2);
    v += __shfl_xor(v, 4); v += __shfl_xor(v, 8);
    os[j] = v;
  }
  __shared__ float osm[4][64];
  if (m == 0){
#pragma unroll
    for (int j = 0; j < 8; j++){
      osm[wid][g * 8 + j]      = os[j];
      osm[wid][32 + g * 8 + j] = os[8 + j];
    }
  }
  __syncthreads();
  if (threadIdx.x < 64)
    atomicAdd(&scal[threadIdx.x],
              osm[0][threadIdx.x] + osm[1][threadIdx.x] + osm[2][threadIdx.x] + osm[3][threadIdx.x]);
}

// ---------------- part2b (1 wave) ----------------
__global__ void k_part2b(float* __restrict__ scal, const float* __restrict__ wm_t,
                         const float* __restrict__ att_dst){
  int lane = threadIdx.x;
  float o = fmaxf(scal[lane], 0.f);
  float acc = 0.f;
  for (int k = 0; k < 64; k++) acc += bcast(o, k) * wm_t[k * 64 + lane];
  float c = wave_sum(acc * att_dst[lane]);
  scal[64 + lane] = o;
  if (lane == 0){
    scal[128] = c;
    float maxtb = funkey(*(unsigned*)(scal + 131));
    scal[130] = lrelu(maxtb + c);   // M = max_n lrelu(tb[n]+c)
  }
}

// ---------------- a2 weighted sums (bf16 xs) ----------------
__global__ void k_a2sum(const float* __restrict__ tb, const ushort* __restrict__ xsb,
                        float* __restrict__ scal, int N){
  int lane = threadIdx.x & 63, w = threadIdx.x >> 6;
  int gw = blockIdx.x * 4 + w, nw = gridDim.x * 4;
  float c = scal[128];
  float M = scal[130];
  float hloc = 0.f, sloc = 0.f;
  for (int n = gw; n < N; n += nw){
    float a2 = lrelu(tb[n] + c);
    float wt = __expf(a2 - M);
    sloc += wt;
    hloc += wt * bf2f(xsb[(size_t)n * 64 + lane]);
  }
  __shared__ float lds[256];
  __shared__ float sred[4];
  lds[threadIdx.x] = hloc;
  if (lane == 0) sred[w] = sloc;
  __syncthreads();
  if (threadIdx.x < 64)
    atomicAdd(&scal[192 + threadIdx.x],
              lds[threadIdx.x] + lds[64 + threadIdx.x] + lds[128 + threadIdx.x] + lds[192 + threadIdx.x]);
  if (threadIdx.x == 0) atomicAdd(&scal[129], sred[0] + sred[1] + sred[2] + sred[3]);
}

// ---------------- final (1 wave, coalesced transposed weights) ----------------
__global__ void k_final(const float* __restrict__ scal, const float* __restrict__ bm,
                        const float* __restrict__ g2ih_t, const float* __restrict__ g2hh_t,
                        const float* __restrict__ bih, const float* __restrict__ bhh,
                        const float* __restrict__ w2_t, const float* __restrict__ b2,
                        float* __restrict__ dout){
  int lane = threadIdx.x;
  float S  = scal[129];
  float h2 = scal[192 + lane] / S + bm[lane];
  float xg = h2 > 0.f ? h2 : __expf(h2) - 1.f;
  float xo = scal[64 + lane];
  float gir = bih[lane], giz = bih[64 + lane], gin = bih[128 + lane];
  float ghr = bhh[lane], ghz = bhh[64 + lane], ghn = bhh[128 + lane];
  for (int k = 0; k < 64; k++){
    float a = bcast(xg, k), b = bcast(xo, k);
    const float* gi = g2ih_t + k * 192;
    const float* gh = g2hh_t + k * 192;
    gir += a * gi[lane]; giz += a * gi[64 + lane]; gin += a * gi[128 + lane];
    ghr += b * gh[lane]; ghz += b * gh[64 + lane]; ghn += b * gh[128 + lane];
  }
  float r  = 1.f / (1.f + __expf(-(gir + ghr)));
  float z  = 1.f / (1.f + __expf(-(giz + ghz)));
  float nn = tanhf(gin + r * ghn);
  float o2 = fmaxf((1.f - z) * nn + z * xo, 0.f);
  float res = 0.f;
  for (int k = 0; k < 64; k++) res += bcast(o2, k) * w2_t[k * 64 + lane];
  dout[lane] = res + b2[lane];
}

extern "C" void kernel_launch(void* const* d_in, const int* in_sizes, int n_in,
                              void* d_out, int out_size, void* d_ws, size_t ws_size,
                              hipStream_t stream){
  const float* na    = (const float*)d_in[0];
  const float* ea    = (const float*)d_in[1];
  const int*   ei    = (const int*)d_in[2];
  const float* w1    = (const float*)d_in[3];
  const float* b1    = (const float*)d_in[4];
  const float* wg1   = (const float*)d_in[5];
  const float* att_l = (const float*)d_in[6];
  const float* att_r = (const float*)d_in[7];
  const float* wg2   = (const float*)d_in[8];
  const float* bg    = (const float*)d_in[9];
  const float* g1wih = (const float*)d_in[10];
  const float* g1whh = (const float*)d_in[11];
  const float* g1bih = (const float*)d_in[12];
  const float* g1bhh = (const float*)d_in[13];
  const float* wm      = (const float*)d_in[14];
  const float* att_src = (const float*)d_in[15];
  const float* att_dst = (const float*)d_in[16];
  const float* bm      = (const float*)d_in[17];
  const float* g2wih = (const float*)d_in[18];
  const float* g2whh = (const float*)d_in[19];
  const float* g2bih = (const float*)d_in[20];
  const float* g2bhh = (const float*)d_in[21];
  const float* w2    = (const float*)d_in[22];
  const float* b2    = (const float*)d_in[23];

  int N = in_sizes[0];
  int E = in_sizes[1];
  const int* srcArr = ei;
  const int* dstArr = ei + E;

  char* ws = (char*)d_ws;
  size_t cur = 0;
  auto alloc = [&](size_t nbytes) -> char* {
    char* p = ws + cur;
    cur += (nbytes + 255) & ~(size_t)255;
    return p;
  };
  ushort* yb   = (ushort*)alloc((size_t)N * 64 * 2);   // bf16 y; reused as xs (bf16) after edge_f
  float* bufC  = (float*)alloc((size_t)N * 64 * 4);    // sout (f32)
  float* xr    = (float*)alloc((size_t)N * 4);
  float* tb    = (float*)alloc((size_t)N * 4);
  int*   offA  = (int*)alloc((size_t)(N + 1) * 4);
  int*   perm  = (int*)alloc((size_t)N * 4);
  int*   bcnt  = (int*)alloc(4096);
  int*   bbase = (int*)alloc(4096);
  int*   gtail = (int*)alloc(4096);
  int*   dcnt  = (int*)alloc(256);
  int*   dtail = (int*)alloc(256);
  int2*  csr   = (int2*)alloc((size_t)E * 8);
  int2*  tse   = (int2*)alloc((size_t)E * 8);   // reused as x2 (bf16) after binB
  float* scal  = (float*)alloc(4096);
  float* wm_t  = (float*)alloc(64 * 64 * 4);
  float* w2_t  = (float*)alloc(64 * 64 * 4);
  float* g2ih_t= (float*)alloc(64 * 192 * 4);
  float* g2hh_t= (float*)alloc(64 * 192 * 4);
  float* wgc   = (float*)alloc(64 * 4);
  ushort* wg2f = (ushort*)alloc(4096 * 2);
  ushort* wmf  = (ushort*)alloc(4096 * 2);
  ushort* wg1f = (ushort*)alloc(4096 * 2);
  ushort* wihf = (ushort*)alloc(12288 * 2);
  ushort* whhf = (ushort*)alloc(12288 * 2);
  if (cur > ws_size) return;

  ushort* x2b = (ushort*)tse;   // x2 bf16 overlays tse (dead after k_binB)
  ushort* xsb = yb;             // xs bf16 overlays yb (dead after k_edge_f)

  hipMemsetAsync(bcnt, 0, 4096, stream);
  hipMemsetAsync(dcnt, 0, 256, stream);
  hipMemsetAsync(scal, 0, 4096, stream);

  k_wprep<<<64, 192, 0, stream>>>(wg1, wm, w2, g2wih, g2whh,
                                  wm_t, w2_t, g2ih_t, g2hh_t, wgc);
  k_wfrag<<<18, 256, 0, stream>>>(wg2, wm, wg1, g1wih, g1whh,
                                  wg2f, wmf, wg1f, wihf, whhf);

  int nbuck = (N + 255) >> BSHIFT;
  int nbA = (E + 4095) / 4096;
  k_node_bh<<<512 + nbA, 256, 0, stream>>>(na, w1, b1, wg1f, att_r, yb, xr, N,
                                           dstArr, bcnt, E, nbuck);
  k_bscan<<<1, 512, 0, stream>>>(bcnt, bbase, gtail, nbuck);
  k_binA<<<nbA, 256, 0, stream>>>(dstArr, srcArr, ea, gtail, tse, E);
  k_binB<<<nbuck, 256, 0, stream>>>(bbase, tse, csr, offA, dcnt, N);
  k_dscan<<<1, 64, 0, stream>>>(dcnt, dtail);
  k_dfill<<<(N + 4095) / 4096, 256, 0, stream>>>(offA, dtail, perm, N);
  int nwb2 = (N + 15) / 16;        // 4 waves/block, 4 nodes/wave
  k_edge_f<<<nwb2, 256, 0, stream>>>(offA, csr, yb, xr, wgc, att_l, perm, bufC, N);
  int ngb = (N + 63) / 64;         // 4 waves/block, 16 nodes/wave (MFMA)
  k_gru1m<<<ngb, 256, 0, stream>>>(bufC, na, w1, b1, wg2f, bg, wihf, whhf,
                                   g1bih, g1bhh, x2b, N);
  k_part2m<<<512, 256, 0, stream>>>(x2b, xsb, wmf, att_src, tb, scal, N);
  k_part2b<<<1, 64, 0, stream>>>(scal, wm_t, att_dst);
  k_a2sum<<<512, 256, 0, stream>>>(tb, xsb, scal, N);
  k_final<<<1, 64, 0, stream>>>(scal, bm, g2ih_t, g2hh_t, g2bih, g2bhh, w2_t, b2, (float*)d_out);
  (void)n_in; (void)out_size;
}

// Round 18
// 232.806 us; speedup vs baseline: 1.0245x; 1.0245x over previous
//
#include <hip/hip_runtime.h>
#include <math.h>

typedef __attribute__((ext_vector_type(8))) short bf8;
typedef __attribute__((ext_vector_type(4))) float f32x4;

#define BSHIFT 8   // 256 nodes per bucket (391 buckets at N=100K -> fills 256 CUs)

__device__ __forceinline__ float lrelu(float v){ return fmaxf(v, 0.01f * v); }

__device__ __forceinline__ float wave_sum(float v){
#pragma unroll
  for (int s = 32; s > 0; s >>= 1) v += __shfl_xor(v, s);
  return v;
}
__device__ __forceinline__ float wave_max(float v){
#pragma unroll
  for (int s = 32; s > 0; s >>= 1) v = fmaxf(v, __shfl_xor(v, s));
  return v;
}

__device__ __forceinline__ float bcast(float v, int k){
  return __uint_as_float((unsigned)__builtin_amdgcn_readlane(__float_as_uint(v), k));
}

// float -> orderable unsigned key (monotone)
__device__ __forceinline__ unsigned fkey(float x){
  unsigned u = __float_as_uint(x);
  return (u & 0x80000000u) ? ~u : (u | 0x80000000u);
}
__device__ __forceinline__ float funkey(unsigned k){
  unsigned u = (k & 0x80000000u) ? (k & 0x7fffffffu) : ~k;
  return __uint_as_float(u);
}

// float -> bf16 (RNE)
__device__ __forceinline__ short f2bfs(float x){
  unsigned u = __float_as_uint(x);
  return (short)((u + 0x7fffu + ((u >> 16) & 1u)) >> 16);
}
__device__ __forceinline__ float bf2f(ushort v){
  return __uint_as_float((unsigned)v << 16);
}
__device__ __forceinline__ bf8 pack8(float4 a, float4 b){
  bf8 v;
  v[0]=f2bfs(a.x); v[1]=f2bfs(a.y); v[2]=f2bfs(a.z); v[3]=f2bfs(a.w);
  v[4]=f2bfs(b.x); v[5]=f2bfs(b.y); v[6]=f2bfs(b.z); v[7]=f2bfs(b.w);
  return v;
}
__device__ __forceinline__ float4 xo4(float nav, float4 w, float4 b){
  float4 r;
  r.x = lrelu(nav*w.x + b.x); r.y = lrelu(nav*w.y + b.y);
  r.z = lrelu(nav*w.z + b.z); r.w = lrelu(nav*w.w + b.w);
  return r;
}
__device__ __forceinline__ float dot4(float4 a, float4 b){
  return a.x*b.x + a.y*b.y + a.z*b.z + a.w*b.w;
}

// ---------------- weight transpose to k-major (small weights for 1-wave kernels) ----------------
__global__ void k_wprep(const float* __restrict__ wg1, const float* __restrict__ wm,
                        const float* __restrict__ w2,
                        const float* __restrict__ g2wih, const float* __restrict__ g2whh,
                        float* __restrict__ wm_t, float* __restrict__ w2_t,
                        float* __restrict__ g2ih_t, float* __restrict__ g2hh_t,
                        float* __restrict__ wgc){
  int k = blockIdx.x;      // 0..63
  int r = threadIdx.x;     // 0..191
  if (r < 64){
    wm_t [k * 64 + r] = wm [r * 64 + k];
    w2_t [k * 64 + r] = w2 [r * 64 + k];
    if (k == 0) wgc[r] = wg1[r * 65 + 64];
  }
  g2ih_t[k * 192 + r] = g2wih[r * 64 + k];
  g2hh_t[k * 192 + r] = g2whh[r * 64 + k];
}

// ---------------- pack weights into bf16 MFMA B-fragments ----------------
// B-frag slot (c, t, lane l, j) <- W[16t + (l&15)][32c + (l>>4)*8 + j], row stride S
__global__ void k_wfrag(const float* __restrict__ wg2, const float* __restrict__ wm,
                        const float* __restrict__ wg1,
                        const float* __restrict__ wih, const float* __restrict__ whh,
                        ushort* __restrict__ wg2f, ushort* __restrict__ wmf,
                        ushort* __restrict__ wg1f,
                        ushort* __restrict__ wihf, ushort* __restrict__ whhf){
  int tid = blockIdx.x * 256 + threadIdx.x;  // 0..4607
  if (tid >= 4608) return;
  const float* W; ushort* F; int T, S, base;
  if (tid < 512)      { W = wg2; F = wg2f; T = 4;  S = 64; base = tid; }
  else if (tid < 1024){ W = wm;  F = wmf;  T = 4;  S = 64; base = tid - 1024 + 512; }
  else if (tid < 1536){ W = wg1; F = wg1f; T = 4;  S = 65; base = tid - 1024; }
  else if (tid < 3072){ W = wih; F = wihf; T = 12; S = 64; base = tid - 1536; }
  else                { W = whh; F = whhf; T = 12; S = 64; base = tid - 3072; }
  int l  = base & 63;
  int ct = base >> 6;
  int c  = ct / T, t = ct - c * T;
  int row = 16 * t + (l & 15);
  int k0  = 32 * c + (l >> 4) * 8;
  const float* src = W + row * S + k0;
  unsigned o0 = (unsigned)(ushort)f2bfs(src[0]) | ((unsigned)(ushort)f2bfs(src[1]) << 16);
  unsigned o1 = (unsigned)(ushort)f2bfs(src[2]) | ((unsigned)(ushort)f2bfs(src[3]) << 16);
  unsigned o2 = (unsigned)(ushort)f2bfs(src[4]) | ((unsigned)(ushort)f2bfs(src[5]) << 16);
  unsigned o3 = (unsigned)(ushort)f2bfs(src[6]) | ((unsigned)(ushort)f2bfs(src[7]) << 16);
  ((uint4*)F)[base] = make_uint4(o0, o1, o2, o3);
}

// ---------------- node prep via MFMA: y(bf16) = x@wg1[:,:64].T, xr = dot(x, att_r) ----------------
__global__ __launch_bounds__(256) void k_node_m(
    const float* __restrict__ na, const float* __restrict__ w1,
    const float* __restrict__ b1, const ushort* __restrict__ wg1f,
    const float* __restrict__ att_r,
    ushort* __restrict__ yb, float* __restrict__ xr, int N){
  int lane = threadIdx.x & 63;
  int wid  = threadIdx.x >> 6;
  int m = lane & 15, g = lane >> 4;
  const bf8* WG = (const bf8*)wg1f;
  float4 w1a = *(const float4*)(w1 + g*8),      w1b = *(const float4*)(w1 + g*8 + 4);
  float4 w1c = *(const float4*)(w1 + 32 + g*8), w1d = *(const float4*)(w1 + 32 + g*8 + 4);
  float4 b1a = *(const float4*)(b1 + g*8),      b1b = *(const float4*)(b1 + g*8 + 4);
  float4 b1c = *(const float4*)(b1 + 32 + g*8), b1d = *(const float4*)(b1 + 32 + g*8 + 4);
  float4 ara = *(const float4*)(att_r + g*8),      arb = *(const float4*)(att_r + g*8 + 4);
  float4 arc = *(const float4*)(att_r + 32 + g*8), ard = *(const float4*)(att_r + 32 + g*8 + 4);
  int ntiles = (N + 15) >> 4;
  for (int tile = blockIdx.x * 4 + wid; tile < ntiles; tile += gridDim.x * 4){
    int n0 = tile * 16;
    int row = n0 + m;
    bool valid = row < N;
    float nav = valid ? na[row] : 0.f;
    float4 x0 = xo4(nav, w1a, b1a), x1 = xo4(nav, w1b, b1b);
    float4 x2 = xo4(nav, w1c, b1c), x3 = xo4(nav, w1d, b1d);
    float xa = dot4(x0, ara) + dot4(x1, arb) + dot4(x2, arc) + dot4(x3, ard);
    xa += __shfl_xor(xa, 16); xa += __shfl_xor(xa, 32);
    if (g == 0 && valid) xr[row] = xa;
    bf8 fa0 = pack8(x0, x1), fa1 = pack8(x2, x3);
    f32x4 yt[4];
#pragma unroll
    for (int t = 0; t < 4; t++){
      f32x4 acc = {0.f, 0.f, 0.f, 0.f};
      acc = __builtin_amdgcn_mfma_f32_16x16x32_bf16(fa0, WG[t * 64 + lane], acc, 0, 0, 0);
      acc = __builtin_amdgcn_mfma_f32_16x16x32_bf16(fa1, WG[(4 + t) * 64 + lane], acc, 0, 0, 0);
      yt[t] = acc;
    }
#pragma unroll
    for (int t = 0; t < 4; t++){
#pragma unroll
      for (int r = 0; r < 4; r++){
        int rw = n0 + g * 4 + r;
        if (rw < N) yb[(size_t)rw * 64 + m + 16 * t] = (ushort)f2bfs(yt[t][r]);
      }
    }
  }
}

// ---------------- bucket histogram (LDS-aggregated) ----------------
__global__ __launch_bounds__(256) void k_bhist(const int* __restrict__ dst,
                                               int* __restrict__ bcnt, int E, int nbuck){
  __shared__ int hist[512];
  hist[threadIdx.x] = 0; hist[256 + threadIdx.x] = 0;
  __syncthreads();
  int e0 = blockIdx.x * 4096;
  int e1 = min(e0 + 4096, E);
  for (int i = e0 + threadIdx.x; i < e1; i += 256)
    atomicAdd(&hist[dst[i] >> BSHIFT], 1);
  __syncthreads();
#pragma unroll
  for (int q = 0; q < 2; q++){
    int j = threadIdx.x + q * 256;
    if (j < nbuck && hist[j] > 0) atomicAdd(&bcnt[j], hist[j]);
  }
}

// ---------------- bucket prefix scan (1 block, 512 threads) ----------------
__global__ void k_bscan(const int* __restrict__ bcnt, int* __restrict__ bbase,
                        int* __restrict__ gtail, int nbuck){
  __shared__ int lds[512];
  int t = threadIdx.x;
  int v = (t < nbuck) ? bcnt[t] : 0;
  lds[t] = v;
  __syncthreads();
  for (int s = 1; s < 512; s <<= 1){
    int tv = (t >= s) ? lds[t - s] : 0;
    __syncthreads();
    lds[t] += tv;
    __syncthreads();
  }
  if (t <= nbuck){
    int excl = (t == 0) ? 0 : lds[t - 1];
    bbase[t] = excl;
    if (t < nbuck) gtail[t] = excl;
  }
}

// ---------------- binned scatter phase A: group edges by dst-bucket (tail-append)
// packed 8B record: {src | drel<<17, ea-bits}
__global__ __launch_bounds__(256) void k_binA(
    const int* __restrict__ dst, const int* __restrict__ src,
    const float* __restrict__ ea, int* __restrict__ gtail,
    int2* __restrict__ tse, int E){
  __shared__ int hist[512], base[512], run[512];
  int e0 = blockIdx.x * 4096;
  int e1 = min(e0 + 4096, E);
  hist[threadIdx.x] = 0; hist[256 + threadIdx.x] = 0;
  run[threadIdx.x] = 0;  run[256 + threadIdx.x] = 0;
  __syncthreads();
  for (int i = e0 + threadIdx.x; i < e1; i += 256)
    atomicAdd(&hist[dst[i] >> BSHIFT], 1);
  __syncthreads();
#pragma unroll
  for (int q = 0; q < 2; q++){
    int j = threadIdx.x + q * 256;
    if (hist[j] > 0) base[j] = atomicAdd(&gtail[j], hist[j]);
  }
  __syncthreads();
  for (int i = e0 + threadIdx.x; i < e1; i += 256){
    int d = dst[i];
    int b = d >> BSHIFT;
    int pos = base[b] + atomicAdd(&run[b], 1);
    tse[pos] = make_int2(src[i] | ((d & 255) << 17), __float_as_int(ea[i]));
  }
}

// ---------------- binned scatter phase B: derive per-node offsets locally + place ----------------
__global__ __launch_bounds__(256) void k_binB(
    const int* __restrict__ bbase, const int2* __restrict__ tse,
    int2* __restrict__ csr, int* __restrict__ off, int N){
  __shared__ int degL[256];
  __shared__ int fillL[256];
  int node0 = blockIdx.x << BSHIFT;
  int node1 = min(node0 + 256, N);
  int nn = node1 - node0;
  int i0 = bbase[blockIdx.x], i1 = bbase[blockIdx.x + 1];
  int t = threadIdx.x;
  degL[t] = 0;
  __syncthreads();
  for (int i = i0 + t; i < i1; i += 256)
    atomicAdd(&degL[(tse[i].x >> 17) & 255], 1);
  __syncthreads();
  // inclusive Hillis-Steele scan over 256 entries
  for (int s = 1; s < 256; s <<= 1){
    int v = (t >= s) ? degL[t - s] : 0;
    __syncthreads();
    degL[t] += v;
    __syncthreads();
  }
  int prev = (t == 0) ? 0 : degL[t - 1];
  fillL[t] = i0 + prev;
  if (t < nn) off[node0 + t] = i0 + prev;
  if (t == 0 && node1 == N) off[N] = i1;
  __syncthreads();
  for (int i = i0 + t; i < i1; i += 256){
    int2 rec = tse[i];
    int drel = (rec.x >> 17) & 255;
    int pos = atomicAdd(&fillL[drel], 1);
    csr[pos] = make_int2(rec.x & 0x1FFFF, rec.y);
  }
}

// ---------------- fused edge kernel: 4 nodes/wave, 16 lanes/node, no-max softmax,
// 2-edge interleaved chains + 4-slot prefetch pipeline (named regs, no runtime indexing)
__global__ void k_edge_f(const int* __restrict__ off, const int2* __restrict__ csr,
                         const ushort* __restrict__ yb, const float* __restrict__ xr,
                         const float* __restrict__ wgc, const float* __restrict__ att_l,
                         float* __restrict__ sout, int N){
  int lane = threadIdx.x & 63;
  int wwid = (blockIdx.x * blockDim.x + threadIdx.x) >> 6;
  int g = lane >> 4, sl = lane & 15;
  int node = wwid * 4 + g;
  if (node >= N) return;
  int i0 = off[node], i1 = off[node + 1];
  float4 wc4 = ((const float4*)wgc)[sl];
  float4 al4 = ((const float4*)att_l)[sl];
  float xrn = xr[node];
  float sg = 0.f;
  float4 acc = make_float4(0.f, 0.f, 0.f, 0.f);
  int cnt = i1 - i0;
  int2 rA = make_int2(0,0), rB = rA, rC = rA, rD = rA;
  ushort4 yA = make_ushort4(0,0,0,0), yB = yA, yC = yA, yD = yA;
  if (cnt > 0){ rA = csr[i0];     yA = ((const ushort4*)(yb + (size_t)rA.x * 64))[sl]; }
  if (cnt > 1){ rB = csr[i0 + 1]; yB = ((const ushort4*)(yb + (size_t)rB.x * 64))[sl]; }
  if (cnt > 2){ rC = csr[i0 + 2]; yC = ((const ushort4*)(yb + (size_t)rC.x * 64))[sl]; }
  if (cnt > 3){ rD = csr[i0 + 3]; yD = ((const ushort4*)(yb + (size_t)rD.x * 64))[sl]; }
  int i = i0;
  for (; i + 1 < i1; i += 2){
    float eaA = __int_as_float(rA.y);
    float eaB = __int_as_float(rB.y);
    float4 heA, heB;
    heA.x = lrelu(bf2f(yA.x) + eaA * wc4.x); heB.x = lrelu(bf2f(yB.x) + eaB * wc4.x);
    heA.y = lrelu(bf2f(yA.y) + eaA * wc4.y); heB.y = lrelu(bf2f(yB.y) + eaB * wc4.y);
    heA.z = lrelu(bf2f(yA.z) + eaA * wc4.z); heB.z = lrelu(bf2f(yB.z) + eaB * wc4.z);
    heA.w = lrelu(bf2f(yA.w) + eaA * wc4.w); heB.w = lrelu(bf2f(yB.w) + eaB * wc4.w);
    // rotate pipeline, issue prefetch for i+4, i+5 (overlaps the reductions below)
    rA = rC; yA = yC; rB = rD; yB = yD;
    if (i + 4 < i1){ rC = csr[i + 4]; yC = ((const ushort4*)(yb + (size_t)rC.x * 64))[sl]; }
    if (i + 5 < i1){ rD = csr[i + 5]; yD = ((const ushort4*)(yb + (size_t)rD.x * 64))[sl]; }
    float pA = dot4(heA, al4), pB = dot4(heB, al4);
    pA += __shfl_xor(pA, 1); pB += __shfl_xor(pB, 1);
    pA += __shfl_xor(pA, 2); pB += __shfl_xor(pB, 2);
    pA += __shfl_xor(pA, 4); pB += __shfl_xor(pB, 4);
    pA += __shfl_xor(pA, 8); pB += __shfl_xor(pB, 8);
    float wa = __expf(lrelu(pA + xrn));
    float wb = __expf(lrelu(pB + xrn));
    sg += wa + wb;
    acc.x += wa * heA.x + wb * heB.x;
    acc.y += wa * heA.y + wb * heB.y;
    acc.z += wa * heA.z + wb * heB.z;
    acc.w += wa * heA.w + wb * heB.w;
  }
  if (i < i1){
    float ea = __int_as_float(rA.y);
    float4 he;
    he.x = lrelu(bf2f(yA.x) + ea * wc4.x);
    he.y = lrelu(bf2f(yA.y) + ea * wc4.y);
    he.z = lrelu(bf2f(yA.z) + ea * wc4.z);
    he.w = lrelu(bf2f(yA.w) + ea * wc4.w);
    float p = dot4(he, al4);
    p += __shfl_xor(p, 1); p += __shfl_xor(p, 2);
    p += __shfl_xor(p, 4); p += __shfl_xor(p, 8);
    float w = __expf(lrelu(p + xrn));
    sg += w;
    acc.x += w * he.x; acc.y += w * he.y;
    acc.z += w * he.z; acc.w += w * he.w;
  }
  float inv = (i1 > i0 && sg > 0.f) ? 1.f / sg : 0.f;
  float4 o = make_float4(acc.x * inv, acc.y * inv, acc.z * inv, acc.w * inv);
  ((float4*)(sout + (size_t)node * 64))[sl] = o;
}

// ---------------- GRU1 via MFMA: block = 64 nodes, wave = 16-node M-tile ----------------
__global__ __launch_bounds__(256) void k_gru1m(
    const float* __restrict__ sout, const float* __restrict__ na,
    const float* __restrict__ w1, const float* __restrict__ b1,
    const ushort* __restrict__ wg2f, const float* __restrict__ bg,
    const ushort* __restrict__ wihf, const ushort* __restrict__ whhf,
    const float* __restrict__ bih, const float* __restrict__ bhh,
    float* __restrict__ x2, int N){
  __shared__ ushort xgl[4][16][72];   // per-wave elu(h) tile, bf16, padded rows
  int lane = threadIdx.x & 63;
  int wid  = threadIdx.x >> 6;
  int m = lane & 15, g = lane >> 4;
  int n0 = blockIdx.x * 64 + wid * 16;
  if (n0 >= N) return;                 // no barriers used -> safe early exit
  int rowc = min(n0 + m, N - 1);
  const float* srow = sout + (size_t)rowc * 64;
  bf8 sa0 = pack8(*(const float4*)(srow + g * 8),      *(const float4*)(srow + g * 8 + 4));
  bf8 sa1 = pack8(*(const float4*)(srow + 32 + g * 8), *(const float4*)(srow + 32 + g * 8 + 4));
  const bf8* WG = (const bf8*)wg2f;
  f32x4 h[4];
#pragma unroll
  for (int t = 0; t < 4; t++){
    f32x4 acc = {0.f, 0.f, 0.f, 0.f};
    acc = __builtin_amdgcn_mfma_f32_16x16x32_bf16(sa0, WG[t * 64 + lane], acc, 0, 0, 0);
    acc = __builtin_amdgcn_mfma_f32_16x16x32_bf16(sa1, WG[(4 + t) * 64 + lane], acc, 0, 0, 0);
    h[t] = acc;
  }
#pragma unroll
  for (int t = 0; t < 4; t++){
    float bgc = bg[m + 16 * t];
#pragma unroll
    for (int r = 0; r < 4; r++){
      float hv = h[t][r] + bgc;
      float xg = hv > 0.f ? hv : __expf(hv) - 1.f;
      xgl[wid][g * 4 + r][m + 16 * t] = (ushort)f2bfs(xg);
    }
  }
  float nav = na[rowc];
  bf8 xoa0 = pack8(xo4(nav, *(const float4*)(w1 + g * 8),      *(const float4*)(b1 + g * 8)),
                   xo4(nav, *(const float4*)(w1 + g * 8 + 4),  *(const float4*)(b1 + g * 8 + 4)));
  bf8 xoa1 = pack8(xo4(nav, *(const float4*)(w1 + 32 + g * 8),     *(const float4*)(b1 + 32 + g * 8)),
                   xo4(nav, *(const float4*)(w1 + 32 + g * 8 + 4), *(const float4*)(b1 + 32 + g * 8 + 4)));
  bf8 xga0 = *(const bf8*)&xgl[wid][m][g * 8];
  bf8 xga1 = *(const bf8*)&xgl[wid][m][32 + g * 8];
  const bf8* WI = (const bf8*)wihf;
  const bf8* WH = (const bf8*)whhf;
#pragma unroll
  for (int t = 0; t < 4; t++){
    f32x4 iR = {0.f,0.f,0.f,0.f}, iZ = iR, iN = iR, hR = iR, hZ = iR, hN = iR;
    iR = __builtin_amdgcn_mfma_f32_16x16x32_bf16(xga0, WI[(t     ) * 64 + lane], iR, 0,0,0);
    iR = __builtin_amdgcn_mfma_f32_16x16x32_bf16(xga1, WI[(12 + t) * 64 + lane], iR, 0,0,0);
    iZ = __builtin_amdgcn_mfma_f32_16x16x32_bf16(xga0, WI[(t +  4) * 64 + lane], iZ, 0,0,0);
    iZ = __builtin_amdgcn_mfma_f32_16x16x32_bf16(xga1, WI[(16 + t) * 64 + lane], iZ, 0,0,0);
    iN = __builtin_amdgcn_mfma_f32_16x16x32_bf16(xga0, WI[(t +  8) * 64 + lane], iN, 0,0,0);
    iN = __builtin_amdgcn_mfma_f32_16x16x32_bf16(xga1, WI[(20 + t) * 64 + lane], iN, 0,0,0);
    hR = __builtin_amdgcn_mfma_f32_16x16x32_bf16(xoa0, WH[(t     ) * 64 + lane], hR, 0,0,0);
    hR = __builtin_amdgcn_mfma_f32_16x16x32_bf16(xoa1, WH[(12 + t) * 64 + lane], hR, 0,0,0);
    hZ = __builtin_amdgcn_mfma_f32_16x16x32_bf16(xoa0, WH[(t +  4) * 64 + lane], hZ, 0,0,0);
    hZ = __builtin_amdgcn_mfma_f32_16x16x32_bf16(xoa1, WH[(16 + t) * 64 + lane], hZ, 0,0,0);
    hN = __builtin_amdgcn_mfma_f32_16x16x32_bf16(xoa0, WH[(t +  8) * 64 + lane], hN, 0,0,0);
    hN = __builtin_amdgcn_mfma_f32_16x16x32_bf16(xoa1, WH[(20 + t) * 64 + lane], hN, 0,0,0);
    int col = m + 16 * t;
    float biR = bih[col], biZ = bih[64 + col], biN = bih[128 + col];
    float bhR = bhh[col], bhZ = bhh[64 + col], bhN = bhh[128 + col];
    float w1c = w1[col], b1c = b1[col];
#pragma unroll
    for (int r = 0; r < 4; r++){
      int node = n0 + g * 4 + r;
      if (node < N){
        float xon = lrelu(na[node] * w1c + b1c);
        float rg = 1.f / (1.f + __expf(-(iR[r] + biR + hR[r] + bhR)));
        float zg = 1.f / (1.f + __expf(-(iZ[r] + biZ + hZ[r] + bhZ)));
        float nn = tanhf(iN[r] + biN + rg * (hN[r] + bhN));
        float xn = (1.f - zg) * nn + zg * xon;
        x2[(size_t)node * 64 + col] = fmaxf(xn, 0.f);
      }
    }
  }
}

// ---------------- part2 via MFMA: xs = x2@wm.T (in-place), tb, osum, max(tb) ----------------
__global__ __launch_bounds__(256) void k_part2m(
    float* __restrict__ xb,            // in: x2 rows; out: xs rows (in-place per tile)
    const ushort* __restrict__ wmf, const float* __restrict__ att_src,
    float* __restrict__ tb, float* __restrict__ scal, int N){
  int lane = threadIdx.x & 63;
  int wid  = threadIdx.x >> 6;
  int m = lane & 15, g = lane >> 4;
  const bf8* WM = (const bf8*)wmf;
  float as_t[4];
#pragma unroll
  for (int t = 0; t < 4; t++) as_t[t] = att_src[m + 16 * t];
  float os[16];
#pragma unroll
  for (int j = 0; j < 16; j++) os[j] = 0.f;
  float tmax = -1e30f;
  int ntiles = (N + 15) >> 4;
  for (int tile = blockIdx.x * 4 + wid; tile < ntiles; tile += gridDim.x * 4){
    int n0 = tile * 16;
    int row = n0 + m;
    bool valid = row < N;
    int rowc = valid ? row : (N - 1);
    const float* xrow = xb + (size_t)rowc * 64;
    float4 a0 = *(const float4*)(xrow + g * 8);
    float4 a1 = *(const float4*)(xrow + g * 8 + 4);
    float4 a2 = *(const float4*)(xrow + 32 + g * 8);
    float4 a3 = *(const float4*)(xrow + 32 + g * 8 + 4);
    if (!valid){ a0 = make_float4(0,0,0,0); a1 = a0; a2 = a0; a3 = a0; }
    os[0]+=a0.x; os[1]+=a0.y; os[2]+=a0.z; os[3]+=a0.w;
    os[4]+=a1.x; os[5]+=a1.y; os[6]+=a1.z; os[7]+=a1.w;
    os[8]+=a2.x; os[9]+=a2.y; os[10]+=a2.z; os[11]+=a2.w;
    os[12]+=a3.x; os[13]+=a3.y; os[14]+=a3.z; os[15]+=a3.w;
    bf8 fa0 = pack8(a0, a1), fa1 = pack8(a2, a3);
    f32x4 xs_t[4];
#pragma unroll
    for (int t = 0; t < 4; t++){
      f32x4 acc = {0.f, 0.f, 0.f, 0.f};
      acc = __builtin_amdgcn_mfma_f32_16x16x32_bf16(fa0, WM[t * 64 + lane], acc, 0, 0, 0);
      acc = __builtin_amdgcn_mfma_f32_16x16x32_bf16(fa1, WM[(4 + t) * 64 + lane], acc, 0, 0, 0);
      xs_t[t] = acc;
    }
    float tpart[4] = {0.f, 0.f, 0.f, 0.f};
#pragma unroll
    for (int t = 0; t < 4; t++){
#pragma unroll
      for (int r = 0; r < 4; r++){
        int rw = n0 + g * 4 + r;
        if (rw < N) xb[(size_t)rw * 64 + m + 16 * t] = xs_t[t][r];
        tpart[r] += xs_t[t][r] * as_t[t];
      }
    }
#pragma unroll
    for (int r = 0; r < 4; r++){
      float v = tpart[r];
      v += __shfl_xor(v, 1); v += __shfl_xor(v, 2);
      v += __shfl_xor(v, 4); v += __shfl_xor(v, 8);
      if (m == 0){
        int rw = n0 + g * 4 + r;
        if (rw < N){ tb[rw] = v; tmax = fmaxf(tmax, v); }
      }
    }
  }
  tmax = wave_max(tmax);
  if (lane == 0) atomicMax((unsigned*)(scal + 131), fkey(tmax));
#pragma unroll
  for (int j = 0; j < 16; j++){
    float v = os[j];
    v += __shfl_xor(v, 1); v += __shfl_xor(v, 2);
    v += __shfl_xor(v, 4); v += __shfl_xor(v, 8);
    os[j] = v;
  }
  __shared__ float osm[4][64];
  if (m == 0){
#pragma unroll
    for (int j = 0; j < 8; j++){
      osm[wid][g * 8 + j]      = os[j];
      osm[wid][32 + g * 8 + j] = os[8 + j];
    }
  }
  __syncthreads();
  if (threadIdx.x < 64)
    atomicAdd(&scal[threadIdx.x],
              osm[0][threadIdx.x] + osm[1][threadIdx.x] + osm[2][threadIdx.x] + osm[3][threadIdx.x]);
}

// ---------------- part2b (1 wave) ----------------
__global__ void k_part2b(float* __restrict__ scal, const float* __restrict__ wm_t,
                         const float* __restrict__ att_dst){
  int lane = threadIdx.x;
  float o = fmaxf(scal[lane], 0.f);
  float acc = 0.f;
  for (int k = 0; k < 64; k++) acc += bcast(o, k) * wm_t[k * 64 + lane];
  float c = wave_sum(acc * att_dst[lane]);
  scal[64 + lane] = o;
  if (lane == 0){
    scal[128] = c;
    float maxtb = funkey(*(unsigned*)(scal + 131));
    scal[130] = lrelu(maxtb + c);   // M = max_n lrelu(tb[n]+c)  (lrelu monotone)
  }
}

// ---------------- a2 weighted sums ----------------
__global__ void k_a2sum(const float* __restrict__ tb, const float* __restrict__ xs,
                        float* __restrict__ scal, int N){
  int lane = threadIdx.x & 63, w = threadIdx.x >> 6;
  int gw = blockIdx.x * 4 + w, nw = gridDim.x * 4;
  float c = scal[128];
  float M = scal[130];
  float hloc = 0.f, sloc = 0.f;
  for (int n = gw; n < N; n += nw){
    float a2 = lrelu(tb[n] + c);
    float wt = __expf(a2 - M);
    sloc += wt;
    hloc += wt * xs[(size_t)n * 64 + lane];
  }
  __shared__ float lds[256];
  __shared__ float sred[4];
  lds[threadIdx.x] = hloc;
  if (lane == 0) sred[w] = sloc;
  __syncthreads();
  if (threadIdx.x < 64)
    atomicAdd(&scal[192 + threadIdx.x],
              lds[threadIdx.x] + lds[64 + threadIdx.x] + lds[128 + threadIdx.x] + lds[192 + threadIdx.x]);
  if (threadIdx.x == 0) atomicAdd(&scal[129], sred[0] + sred[1] + sred[2] + sred[3]);
}

// ---------------- final (1 wave, coalesced transposed weights) ----------------
__global__ void k_final(const float* __restrict__ scal, const float* __restrict__ bm,
                        const float* __restrict__ g2ih_t, const float* __restrict__ g2hh_t,
                        const float* __restrict__ bih, const float* __restrict__ bhh,
                        const float* __restrict__ w2_t, const float* __restrict__ b2,
                        float* __restrict__ dout){
  int lane = threadIdx.x;
  float S  = scal[129];
  float h2 = scal[192 + lane] / S + bm[lane];
  float xg = h2 > 0.f ? h2 : __expf(h2) - 1.f;
  float xo = scal[64 + lane];
  float gir = bih[lane], giz = bih[64 + lane], gin = bih[128 + lane];
  float ghr = bhh[lane], ghz = bhh[64 + lane], ghn = bhh[128 + lane];
  for (int k = 0; k < 64; k++){
    float a = bcast(xg, k), b = bcast(xo, k);
    const float* gi = g2ih_t + k * 192;
    const float* gh = g2hh_t + k * 192;
    gir += a * gi[lane]; giz += a * gi[64 + lane]; gin += a * gi[128 + lane];
    ghr += b * gh[lane]; ghz += b * gh[64 + lane]; ghn += b * gh[128 + lane];
  }
  float r  = 1.f / (1.f + __expf(-(gir + ghr)));
  float z  = 1.f / (1.f + __expf(-(giz + ghz)));
  float nn = tanhf(gin + r * ghn);
  float o2 = fmaxf((1.f - z) * nn + z * xo, 0.f);
  float res = 0.f;
  for (int k = 0; k < 64; k++) res += bcast(o2, k) * w2_t[k * 64 + lane];
  dout[lane] = res + b2[lane];
}

extern "C" void kernel_launch(void* const* d_in, const int* in_sizes, int n_in,
                              void* d_out, int out_size, void* d_ws, size_t ws_size,
                              hipStream_t stream){
  const float* na    = (const float*)d_in[0];
  const float* ea    = (const float*)d_in[1];
  const int*   ei    = (const int*)d_in[2];
  const float* w1    = (const float*)d_in[3];
  const float* b1    = (const float*)d_in[4];
  const float* wg1   = (const float*)d_in[5];
  const float* att_l = (const float*)d_in[6];
  const float* att_r = (const float*)d_in[7];
  const float* wg2   = (const float*)d_in[8];
  const float* bg    = (const float*)d_in[9];
  const float* g1wih = (const float*)d_in[10];
  const float* g1whh = (const float*)d_in[11];
  const float* g1bih = (const float*)d_in[12];
  const float* g1bhh = (const float*)d_in[13];
  const float* wm      = (const float*)d_in[14];
  const float* att_src = (const float*)d_in[15];
  const float* att_dst = (const float*)d_in[16];
  const float* bm      = (const float*)d_in[17];
  const float* g2wih = (const float*)d_in[18];
  const float* g2whh = (const float*)d_in[19];
  const float* g2bih = (const float*)d_in[20];
  const float* g2bhh = (const float*)d_in[21];
  const float* w2    = (const float*)d_in[22];
  const float* b2    = (const float*)d_in[23];

  int N = in_sizes[0];
  int E = in_sizes[1];
  const int* srcArr = ei;
  const int* dstArr = ei + E;

  char* ws = (char*)d_ws;
  size_t cur = 0;
  auto alloc = [&](size_t nbytes) -> char* {
    char* p = ws + cur;
    cur += (nbytes + 255) & ~(size_t)255;
    return p;
  };
  ushort* yb   = (ushort*)alloc((size_t)N * 64 * 2);   // bf16 y
  float* bufC  = (float*)alloc((size_t)N * 64 * 4);    // sout -> x2 -> xs
  float* xr    = (float*)alloc((size_t)N * 4);
  float* tb    = (float*)alloc((size_t)N * 4);
  int*   offA  = (int*)alloc((size_t)(N + 1) * 4);
  int*   bcnt  = (int*)alloc(4096);
  int*   bbase = (int*)alloc(4096);
  int*   gtail = (int*)alloc(4096);
  int2*  csr   = (int2*)alloc((size_t)E * 8);
  int2*  tse   = (int2*)alloc((size_t)E * 8);
  float* scal  = (float*)alloc(4096);
  float* wm_t  = (float*)alloc(64 * 64 * 4);
  float* w2_t  = (float*)alloc(64 * 64 * 4);
  float* g2ih_t= (float*)alloc(64 * 192 * 4);
  float* g2hh_t= (float*)alloc(64 * 192 * 4);
  float* wgc   = (float*)alloc(64 * 4);
  ushort* wg2f = (ushort*)alloc(4096 * 2);
  ushort* wmf  = (ushort*)alloc(4096 * 2);
  ushort* wg1f = (ushort*)alloc(4096 * 2);
  ushort* wihf = (ushort*)alloc(12288 * 2);
  ushort* whhf = (ushort*)alloc(12288 * 2);
  if (cur > ws_size) return;

  hipMemsetAsync(bcnt, 0, 4096, stream);
  hipMemsetAsync(scal, 0, 4096, stream);

  k_wprep<<<64, 192, 0, stream>>>(wg1, wm, w2, g2wih, g2whh,
                                  wm_t, w2_t, g2ih_t, g2hh_t, wgc);
  k_wfrag<<<18, 256, 0, stream>>>(wg2, wm, wg1, g1wih, g1whh,
                                  wg2f, wmf, wg1f, wihf, whhf);

  int nbuck = (N + 255) >> BSHIFT;
  k_node_m<<<512, 256, 0, stream>>>(na, w1, b1, wg1f, att_r, yb, xr, N);
  k_bhist<<<(E + 4095) / 4096, 256, 0, stream>>>(dstArr, bcnt, E, nbuck);
  k_bscan<<<1, 512, 0, stream>>>(bcnt, bbase, gtail, nbuck);
  k_binA<<<(E + 4095) / 4096, 256, 0, stream>>>(dstArr, srcArr, ea, gtail, tse, E);
  k_binB<<<nbuck, 256, 0, stream>>>(bbase, tse, csr, offA, N);
  int nwb2 = (N + 15) / 16;        // 4 waves/block, 4 nodes/wave
  k_edge_f<<<nwb2, 256, 0, stream>>>(offA, csr, yb, xr, wgc, att_l, bufC, N);
  int ngb = (N + 63) / 64;         // 4 waves/block, 16 nodes/wave (MFMA)
  k_gru1m<<<ngb, 256, 0, stream>>>(bufC, na, w1, b1, wg2f, bg, wihf, whhf,
                                   g1bih, g1bhh, bufC, N);
  k_part2m<<<512, 256, 0, stream>>>(bufC, wmf, att_src, tb, scal, N);
  k_part2b<<<1, 64, 0, stream>>>(scal, wm_t, att_dst);
  k_a2sum<<<512, 256, 0, stream>>>(tb, bufC, scal, N);
  k_final<<<1, 64, 0, stream>>>(scal, bm, g2ih_t, g2hh_t, g2bih, g2bhh, w2_t, b2, (float*)d_out);
  (void)n_in; (void)out_size;
}